// Round 14
// baseline (366.355 us; speedup 1.0000x reference)
//
#include <hip/hip_runtime.h>
#include <hip/hip_bf16.h>

#define D 64
#define FP_SCALE 262144.0f          // 2^18 (order-free int accumulation)
#define FP_INV   (1.0f / 262144.0f)
#define NPC 64                      // nodes per chunk
#define LOG_NPC 6
#define ASTR 65                     // odd acc stride (ints): bank = slot + j*16 + i16 (mod 32)

__device__ __forceinline__ unsigned short f2bf(float f) {   // rtne f32->bf16
    unsigned int u = __float_as_uint(f);
    u += 0x7fffu + ((u >> 16) & 1u);
    return (unsigned short)(u >> 16);
}

// ---------- bucket-granularity CSR build (deterministic) ----------
// bucket = dst>>2 (4 nodes each, 16 buckets per 64-node chunk). Within-bucket
// order is atomic-arrival nondeterministic, but the aggregate's integer
// accumulation is order-free -> output is a pure function of the inputs.
__global__ void hist_kernel(const int* __restrict__ dst, int* __restrict__ bktCnt, int E) {
    int e = blockIdx.x * blockDim.x + threadIdx.x;
    if (e < E) atomicAdd(&bktCnt[dst[e] >> 2], 1);
}

// single-block exclusive scan over nbkt bucket counts -> bucketStart AND cursor
__global__ void scan_kernel(const int* __restrict__ bktCnt, int* __restrict__ bucketStart,
                            int* __restrict__ cursor, int nbkt) {
    __shared__ int wsum[8];
    int t = threadIdx.x, lane = t & 63, w = t >> 6;
    int carry = 0;
    for (int base = 0; base < nbkt; base += 512) {
        int i = base + t;
        int v = (i < nbkt) ? bktCnt[i] : 0;
        int incl = v;
        #pragma unroll
        for (int off = 1; off < 64; off <<= 1) {
            int x = __shfl_up(incl, off);
            if (lane >= off) incl += x;
        }
        if (lane == 63) wsum[w] = incl;
        __syncthreads();
        int wpre = 0;
        for (int j = 0; j < w; ++j) wpre += wsum[j];
        int tot = 0;
        for (int j = 0; j < 8; ++j) tot += wsum[j];
        if (i < nbkt) {
            int st = carry + wpre + incl - v;
            bucketStart[i] = st;
            cursor[i] = st;
        }
        carry += tot;
        __syncthreads();
    }
    if (t == 0) bucketStart[nbkt] = carry;   // sentinel = E
}

// Pack (w*2^18, src, slot=dst&63) into one uint64 per edge, bucketed.
__global__ void fill_kernel(const int* __restrict__ src, const int* __restrict__ dst,
                            const float* __restrict__ ew, int* __restrict__ cursor,
                            unsigned long long* __restrict__ perm64, int E) {
    int e = blockIdx.x * blockDim.x + threadIdx.x;
    if (e < E) {
        int d = dst[e];
        int p = atomicAdd(&cursor[d >> 2], 1);
        unsigned lo = ((unsigned)src[e] << LOG_NPC) | (unsigned)(d & (NPC - 1));
        perm64[p] = ((unsigned long long)__float_as_uint(ew[e] * FP_SCALE) << 32) | lo;
    }
}

// ---------- fused aggregate + linear + relu, node-partitioned ----------
// Block owns NPC=64 consecutive nodes = 16 buckets of 4 nodes. Group r
// (16 lanes) owns bucket bid*16+r EXCLUSIVELY: no two groups ever update the
// same node -> zero same-address atomic contention (rounds 12/13's interleaved
// edge mapping had waves colliding on one node's 64 words -> 8-14M conflict
// cycles). Wave's groups r=4*gl+w4 -> slots 16 apart -> atomic bank windows
// (slot+j*16+i16 mod 32) pair up -> 2 lanes/bank = free.
// LDS swizzle (ASTR=65): feature f of slot s at word s*65 + (f&3)*16 + (f>>2).
// Flush: wave owns 16 nodes, o[16] static accumulators; acc reads are
// same-address broadcasts (+0/+16 and +32/+48 pairs ds_read2-fusable);
// Wt[f][lane] consecutive-lane reads conflict-free.
template<bool IN_F32, bool OUT_BF>
__global__ void agg_fused_kernel(const void* __restrict__ xin,
                                 const unsigned long long* __restrict__ perm64,
                                 const int* __restrict__ bucketStart,
                                 const float* __restrict__ W,
                                 const float* __restrict__ bias,
                                 void* __restrict__ xout,
                                 int N) {
    __shared__ int acc[NPC * ASTR];   // 16.6 KB
    __shared__ float Wt[D][D];        // 16 KB, transposed + FP_INV folded
    __shared__ float bsh[D];
    int t = threadIdx.x;
    int bid = blockIdx.x;
    int nodeBase = bid * NPC;
    int nodeEnd = min(nodeBase + NPC, N);

    for (int i = t; i < NPC * ASTR / 4; i += 256)
        reinterpret_cast<int4*>(acc)[i] = make_int4(0, 0, 0, 0);
    // (NPC*ASTR = 4160 = 1040*4, no tail)
    for (int i = t; i < D * D; i += 256) {           // one-time transpose
        int j = i >> 6, d = i & 63;
        Wt[d][j] = W[i] * FP_INV;
    }
    if (t < D) bsh[t] = bias[t];
    __syncthreads();

    int g = t >> 4;               // group 0..15 (16 lanes)
    int i16 = t & 15;             // lane in group: features 4*i16..+3
    int gl = g & 3;
    int w4 = g >> 2;
    int r = gl * 4 + w4;          // this group's bucket (slots 4r..4r+3)

#define EDGE_ATOMIC(pk)                                                         \
    {                                                                           \
        unsigned lo_ = (unsigned)(pk);                                          \
        float w_ = __uint_as_float((unsigned)((pk) >> 32));                     \
        int slot_ = (int)(lo_ & (NPC - 1));                                     \
        int s_ = (int)(lo_ >> LOG_NPC);                                         \
        float v0_, v1_, v2_, v3_;                                               \
        if (IN_F32) {                                                           \
            float4 u_ = *reinterpret_cast<const float4*>(                       \
                (const float*)xin + (size_t)s_ * D + (i16 << 2));               \
            v0_ = u_.x; v1_ = u_.y; v2_ = u_.z; v3_ = u_.w;                     \
        } else {                                                                \
            uint2 u_ = *reinterpret_cast<const uint2*>(                         \
                (const unsigned short*)xin + (size_t)s_ * D + (i16 << 2));      \
            v0_ = __uint_as_float(u_.x << 16);                                  \
            v1_ = __uint_as_float(u_.x & 0xffff0000u);                          \
            v2_ = __uint_as_float(u_.y << 16);                                  \
            v3_ = __uint_as_float(u_.y & 0xffff0000u);                          \
        }                                                                       \
        int base_ = slot_ * ASTR + i16;                                         \
        atomicAdd(&acc[base_ +  0], (int)(w_ * v0_));                           \
        atomicAdd(&acc[base_ + 16], (int)(w_ * v1_));                           \
        atomicAdd(&acc[base_ + 32], (int)(w_ * v2_));                           \
        atomicAdd(&acc[base_ + 48], (int)(w_ * v3_));                           \
    }

    int bs0 = bucketStart[bid * 16 + r];
    int bs1 = bucketStart[bid * 16 + r + 1];
    int e = bs0;
    for (; e + 4 <= bs1; e += 4) {             // batch 4: gathers all in flight
        unsigned long long pk0 = perm64[e + 0];
        unsigned long long pk1 = perm64[e + 1];
        unsigned long long pk2 = perm64[e + 2];
        unsigned long long pk3 = perm64[e + 3];
        EDGE_ATOMIC(pk0); EDGE_ATOMIC(pk1); EDGE_ATOMIC(pk2); EDGE_ATOMIC(pk3);
    }
    for (; e < bs1; ++e) {
        unsigned long long pk = perm64[e];
        EDGE_ATOMIC(pk);
    }
#undef EDGE_ATOMIC
    __syncthreads();

    // flush: wave owns 16 nodes; un-swizzle via broadcast reads
    int wave = t >> 6, lane = t & 63;
    int sBase = wave * 16;
    float o[16];
    #pragma unroll
    for (int i = 0; i < 16; ++i) o[i] = 0.f;
    for (int q = 0; q < 16; ++q) {
        float w0 = Wt[4 * q + 0][lane];
        float w1 = Wt[4 * q + 1][lane];
        float w2 = Wt[4 * q + 2][lane];
        float w3 = Wt[4 * q + 3][lane];
        #pragma unroll
        for (int i = 0; i < 16; ++i) {
            int base = (sBase + i) * ASTR + q;
            float a0 = (float)acc[base +  0];
            float a1 = (float)acc[base + 16];
            float a2 = (float)acc[base + 32];
            float a3 = (float)acc[base + 48];
            o[i] = fmaf(a0, w0, fmaf(a1, w1, fmaf(a2, w2, fmaf(a3, w3, o[i]))));
        }
    }
    #pragma unroll
    for (int i = 0; i < 16; ++i) {
        int node = nodeBase + sBase + i;
        if (node < nodeEnd) {
            float v = fmaxf(bsh[lane] + o[i], 0.0f);
            size_t off = (size_t)node * D + lane;
            if (OUT_BF) ((unsigned short*)xout)[off] = f2bf(v);
            else        ((float*)xout)[off] = v;
        }
    }
}

// ---------- fallback (int-atomic path, deterministic, f32) if ws too small ----------
__global__ void rpi_scatter_kernel(const float* __restrict__ x,
                                   const int* __restrict__ src,
                                   const int* __restrict__ dst,
                                   const float* __restrict__ ew,
                                   int* __restrict__ agg, int E) {
    int tid = blockIdx.x * blockDim.x + threadIdx.x;
    int e = tid >> 4;
    if (e >= E) return;
    int c = (tid & 15) << 2;
    int s = src[e], d = dst[e];
    float w = ew[e] * FP_SCALE;
    float4 v = *reinterpret_cast<const float4*>(&x[(size_t)s * D + c]);
    int* o = &agg[(size_t)d * D + c];
    atomicAdd(o + 0, (int)(w * v.x));
    atomicAdd(o + 1, (int)(w * v.y));
    atomicAdd(o + 2, (int)(w * v.z));
    atomicAdd(o + 3, (int)(w * v.w));
}

__global__ void rpi_linear_relu_kernel(const int* __restrict__ agg,
                                       const float* __restrict__ W,
                                       const float* __restrict__ b,
                                       float* __restrict__ out, int N) {
    __shared__ float Ws[D][D + 1];
    __shared__ float bs[D];
    int t = threadIdx.x;
    for (int i = t; i < D * D; i += 256) Ws[i >> 6][i & 63] = W[i];
    if (t < D) bs[t] = b[t];
    __syncthreads();
    int wave = t >> 6, lane = t & 63;
    int nwaves = gridDim.x * 4;
    for (int n = blockIdx.x * 4 + wave; n < N; n += nwaves) {
        const int* arow = &agg[(size_t)n * D];
        float acc = bs[lane];
        #pragma unroll
        for (int d = 0; d < D; ++d) acc = fmaf((float)arow[d] * FP_INV, Ws[lane][d], acc);
        out[(size_t)n * D + lane] = fmaxf(acc, 0.0f);
    }
}

extern "C" void kernel_launch(void* const* d_in, const int* in_sizes, int n_in,
                              void* d_out, int out_size, void* d_ws, size_t ws_size,
                              hipStream_t stream) {
    const float* x0 = (const float*)d_in[0];   // [N, 64]
    const int*   ei = (const int*)d_in[1];     // [2, E]
    const float* ew = (const float*)d_in[2];   // [E]
    const float* W  = (const float*)d_in[3];   // [64, 64]
    const float* b  = (const float*)d_in[4];   // [64]
    float* out = (float*)d_out;                // [N, 64]

    int N = in_sizes[0] / D;
    int E = in_sizes[2];
    const int* src = ei;
    const int* dst = ei + E;

    int nblk = (N + NPC - 1) / NPC;
    int nbkt = nblk * 16;                      // 4 nodes per bucket
    size_t xeb = (size_t)N * D * sizeof(unsigned short);   // 12.8 MB
    size_t off = 0;
    size_t o_xb1 = off; off += xeb;
    size_t o_xb2 = off; off += xeb;
    size_t o_p64 = off; off += (size_t)E * sizeof(unsigned long long);
    size_t o_cnt = off; off += (size_t)nbkt * sizeof(int);
    size_t o_bs  = off; off += ((size_t)nbkt + 2) * sizeof(int);
    size_t o_cur = off; off += ((size_t)nbkt + 2) * sizeof(int);
    size_t need = off;

    if (ws_size >= need) {
        unsigned short* xb1 = (unsigned short*)((char*)d_ws + o_xb1);
        unsigned short* xb2 = (unsigned short*)((char*)d_ws + o_xb2);
        unsigned long long* perm64 = (unsigned long long*)((char*)d_ws + o_p64);
        int* bktCnt      = (int*)((char*)d_ws + o_cnt);
        int* bucketStart = (int*)((char*)d_ws + o_bs);
        int* cursor      = (int*)((char*)d_ws + o_cur);

        int eb = (E + 255) / 256;

        hipMemsetAsync(bktCnt, 0, (size_t)nbkt * sizeof(int), stream);
        hist_kernel<<<eb, 256, 0, stream>>>(dst, bktCnt, E);
        scan_kernel<<<1, 512, 0, stream>>>(bktCnt, bucketStart, cursor, nbkt);
        fill_kernel<<<eb, 256, 0, stream>>>(src, dst, ew, cursor, perm64, E);

        // iter 0 reads f32 x0 directly (no cvt pass); iters ping-pong bf16
        agg_fused_kernel<true,  true> <<<nblk, 256, 0, stream>>>(x0,  perm64, bucketStart, W, b, xb2, N);
        agg_fused_kernel<false, true> <<<nblk, 256, 0, stream>>>(xb2, perm64, bucketStart, W, b, xb1, N);
        agg_fused_kernel<false, false><<<nblk, 256, 0, stream>>>(xb1, perm64, bucketStart, W, b, out, N);
    } else {
        int* agg = (int*)d_ws;
        const float* xcur = x0;
        int sb = (E * 16 + 255) / 256;
        for (int it = 0; it < 3; ++it) {
            hipMemsetAsync(agg, 0, (size_t)N * D * sizeof(int), stream);
            rpi_scatter_kernel<<<sb, 256, 0, stream>>>(xcur, src, dst, ew, agg, E);
            rpi_linear_relu_kernel<<<2048, 256, 0, stream>>>(agg, W, b, out, N);
            xcur = out;
        }
    }
}

// Round 15
// 300.676 us; speedup vs baseline: 1.2184x; 1.2184x over previous
//
#include <hip/hip_runtime.h>
#include <hip/hip_bf16.h>

#define D 64
#define FP_SCALE 262144.0f          // 2^18 (order-free int accumulation)
#define FP_INV   (1.0f / 262144.0f)
#define NPC 64                      // nodes per chunk
#define ASTR 65                     // odd acc stride (ints)

__device__ __forceinline__ unsigned short f2bf(float f) {   // rtne f32->bf16
    unsigned int u = __float_as_uint(f);
    u += 0x7fffu + ((u >> 16) & 1u);
    return (unsigned short)(u >> 16);
}

// ---------- CSR build (round-12 proven chain, deterministic) ----------
__global__ void hist_kernel(const int* __restrict__ dst, int* __restrict__ counts, int E) {
    int e = blockIdx.x * blockDim.x + threadIdx.x;
    if (e < E) atomicAdd(&counts[dst[e]], 1);
}

__global__ void part_kernel(const int* __restrict__ counts, int* __restrict__ partial, int N) {
    __shared__ int ws4[4];
    int t = threadIdx.x, lane = t & 63, w = t >> 6;
    int n = blockIdx.x * 256 + t;
    int c = (n < N) ? counts[n] : 0;
    #pragma unroll
    for (int off = 32; off > 0; off >>= 1) c += __shfl_down(c, off);
    if (lane == 0) ws4[w] = c;
    __syncthreads();
    if (t == 0) partial[blockIdx.x] = ws4[0] + ws4[1] + ws4[2] + ws4[3];
}

__global__ void scan_kernel(int* __restrict__ partial, int nb) {
    __shared__ int wsum[8];
    int t = threadIdx.x, lane = t & 63, w = t >> 6;
    int carry = 0;
    for (int base = 0; base < nb; base += 512) {
        int i = base + t;
        int v = (i < nb) ? partial[i] : 0;
        int incl = v;
        #pragma unroll
        for (int off = 1; off < 64; off <<= 1) {
            int x = __shfl_up(incl, off);
            if (lane >= off) incl += x;
        }
        if (lane == 63) wsum[w] = incl;
        __syncthreads();
        int wpre = 0;
        for (int j = 0; j < w; ++j) wpre += wsum[j];
        int tot = 0;
        for (int j = 0; j < 8; ++j) tot += wsum[j];
        if (i < nb) partial[i] = carry + wpre + incl - v;
        carry += tot;
        __syncthreads();
    }
}

__global__ void seg_kernel(const int* __restrict__ counts, const int* __restrict__ partial,
                           int* __restrict__ cursor, int* __restrict__ blockStart, int N) {
    __shared__ int ws4[4];
    int t = threadIdx.x, lane = t & 63, w = t >> 6;
    int n = blockIdx.x * 256 + t;
    int c = (n < N) ? counts[n] : 0;
    int incl = c;
    #pragma unroll
    for (int off = 1; off < 64; off <<= 1) {
        int x = __shfl_up(incl, off);
        if (lane >= off) incl += x;
    }
    if (lane == 63) ws4[w] = incl;
    __syncthreads();
    int wpre = 0;
    for (int j = 0; j < w; ++j) wpre += ws4[j];
    int st = partial[blockIdx.x] + wpre + incl - c;
    if (n < N) {
        cursor[n] = st;
        if ((n & (NPC - 1)) == 0) blockStart[n / NPC] = st;
    }
}

// Pack (w*2^18, src, slot=dst&63) into one uint64 per edge. Within-segment
// placement is atomic-order nondeterministic, but the aggregate's integer
// accumulation is order-free -> output is a pure function of the inputs.
__global__ void fill_kernel(const int* __restrict__ src, const int* __restrict__ dst,
                            const float* __restrict__ ew, int* __restrict__ cursor,
                            unsigned long long* __restrict__ perm64, int E) {
    int e = blockIdx.x * blockDim.x + threadIdx.x;
    if (e < E) {
        int d = dst[e];
        int p = atomicAdd(&cursor[d], 1);
        unsigned lo = ((unsigned)src[e] << 6) | (unsigned)(d & (NPC - 1));
        perm64[p] = ((unsigned long long)__float_as_uint(ew[e] * FP_SCALE) << 32) | lo;
    }
}

// ---------- fused aggregate + linear + relu (round-12 structure) ----------
// Block owns NPC=64 nodes -> dst-sorted edge range [es,ee) (~512 edges).
// LDS swizzle (ASTR=65): feature f of slot s at word s*65 + (f&3)*16 + (f>>2).
// Edge mapping: block-uniform 128-edge superblocks; group slice = 8
// consecutive edges (batch-8 -> 8 gathers in flight); loop bounds uniform
// across the block -> no divergence (rounds 13/14's private per-group streams
// lost L2 reuse: FETCH 42->91MB, and diverged).
// Wt stored bf16 (FP_INV folded, exact pow2): LDS 25.1KB -> 6 blocks/CU
// (round 12's 33.2KB f32 Wt capped at 4 blocks / 32% occupancy).
// ~8M bank-conflict cycles = LDS-atomic RMW floor (measured invariant across
// rounds 12/13/14 addressing schemes) — not worth further chasing.
template<bool IN_F32, bool OUT_BF>
__global__ void agg_fused_kernel(const void* __restrict__ xin,
                                 const unsigned long long* __restrict__ perm64,
                                 const int* __restrict__ blockStart,
                                 const float* __restrict__ W,
                                 const float* __restrict__ bias,
                                 void* __restrict__ xout,
                                 int N, int E) {
    __shared__ int acc[NPC * ASTR];        // 16.6 KB
    __shared__ unsigned short Wtb[D][D];   // 8.2 KB: bf16(W^T * FP_INV)
    __shared__ float bsh[D];
    int t = threadIdx.x;
    int bid = blockIdx.x;
    int nodeBase = bid * NPC;
    int nodeEnd = min(nodeBase + NPC, N);
    int es = blockStart[bid];
    int ee = (bid + 1 < (int)gridDim.x) ? blockStart[bid + 1] : E;

    for (int i = t; i < NPC * ASTR / 4; i += 256)
        reinterpret_cast<int4*>(acc)[i] = make_int4(0, 0, 0, 0);
    for (int i = t; i < D * D; i += 256) {   // one-time transpose + bf16 pack
        int j = i >> 6, d = i & 63;
        Wtb[d][j] = f2bf(W[i] * FP_INV);     // *FP_INV exact (pow2 exponent shift)
    }
    if (t < D) bsh[t] = bias[t];
    __syncthreads();

    int g = t >> 4;               // group 0..15 (16 lanes)
    int i16 = t & 15;             // lane in group: features 4*i16..+3
    int gl = g & 3;               // position within wave
    int w4 = g >> 2;              // wave index

#define EDGE_ATOMIC(pk)                                                         \
    {                                                                           \
        unsigned lo_ = (unsigned)(pk);                                          \
        float w_ = __uint_as_float((unsigned)((pk) >> 32));                     \
        int slot_ = (int)(lo_ & (NPC - 1));                                     \
        int s_ = (int)(lo_ >> 6);                                               \
        float v0_, v1_, v2_, v3_;                                               \
        if (IN_F32) {                                                           \
            float4 u_ = *reinterpret_cast<const float4*>(                       \
                (const float*)xin + (size_t)s_ * D + (i16 << 2));               \
            v0_ = u_.x; v1_ = u_.y; v2_ = u_.z; v3_ = u_.w;                     \
        } else {                                                                \
            uint2 u_ = *reinterpret_cast<const uint2*>(                         \
                (const unsigned short*)xin + (size_t)s_ * D + (i16 << 2));      \
            v0_ = __uint_as_float(u_.x << 16);                                  \
            v1_ = __uint_as_float(u_.x & 0xffff0000u);                          \
            v2_ = __uint_as_float(u_.y << 16);                                  \
            v3_ = __uint_as_float(u_.y & 0xffff0000u);                          \
        }                                                                       \
        int base_ = slot_ * ASTR + i16;                                         \
        atomicAdd(&acc[base_ +  0], (int)(w_ * v0_));                           \
        atomicAdd(&acc[base_ + 16], (int)(w_ * v1_));                           \
        atomicAdd(&acc[base_ + 32], (int)(w_ * v2_));                           \
        atomicAdd(&acc[base_ + 48], (int)(w_ * v3_));                           \
    }

    // 128-edge superblocks: group slice = 8 consecutive edges (batch-8),
    // wave's 4 groups 32 apart; bounds uniform across block.
    int myOff = es + gl * 32 + w4 * 8;
    int cnt = ee - es;
    int kmax = cnt >> 7;
    for (int k = 0; k < kmax; ++k) {
        int e0 = myOff + (k << 7);
        unsigned long long pk0 = perm64[e0 + 0];
        unsigned long long pk1 = perm64[e0 + 1];
        unsigned long long pk2 = perm64[e0 + 2];
        unsigned long long pk3 = perm64[e0 + 3];
        unsigned long long pk4 = perm64[e0 + 4];
        unsigned long long pk5 = perm64[e0 + 5];
        unsigned long long pk6 = perm64[e0 + 6];
        unsigned long long pk7 = perm64[e0 + 7];
        EDGE_ATOMIC(pk0); EDGE_ATOMIC(pk1); EDGE_ATOMIC(pk2); EDGE_ATOMIC(pk3);
        EDGE_ATOMIC(pk4); EDGE_ATOMIC(pk5); EDGE_ATOMIC(pk6); EDGE_ATOMIC(pk7);
    }
    for (int e = es + (kmax << 7) + g; e < ee; e += 16) {   // tail
        unsigned long long pk = perm64[e];
        EDGE_ATOMIC(pk);
    }
#undef EDGE_ATOMIC
    __syncthreads();

    // flush: wave owns 16 nodes; un-swizzle via broadcast reads; Wtb bf16
    int wave = t >> 6, lane = t & 63;
    int sBase = wave * 16;
    float o[16];
    #pragma unroll
    for (int i = 0; i < 16; ++i) o[i] = 0.f;
    for (int q = 0; q < 16; ++q) {
        float w0 = __uint_as_float((unsigned)Wtb[4 * q + 0][lane] << 16);
        float w1 = __uint_as_float((unsigned)Wtb[4 * q + 1][lane] << 16);
        float w2 = __uint_as_float((unsigned)Wtb[4 * q + 2][lane] << 16);
        float w3 = __uint_as_float((unsigned)Wtb[4 * q + 3][lane] << 16);
        #pragma unroll
        for (int i = 0; i < 16; ++i) {
            int base = (sBase + i) * ASTR + q;
            float a0 = (float)acc[base +  0];
            float a1 = (float)acc[base + 16];
            float a2 = (float)acc[base + 32];
            float a3 = (float)acc[base + 48];
            o[i] = fmaf(a0, w0, fmaf(a1, w1, fmaf(a2, w2, fmaf(a3, w3, o[i]))));
        }
    }
    #pragma unroll
    for (int i = 0; i < 16; ++i) {
        int node = nodeBase + sBase + i;
        if (node < nodeEnd) {
            float v = fmaxf(bsh[lane] + o[i], 0.0f);
            size_t off = (size_t)node * D + lane;
            if (OUT_BF) ((unsigned short*)xout)[off] = f2bf(v);
            else        ((float*)xout)[off] = v;
        }
    }
}

// ---------- fallback (int-atomic path, deterministic, f32) if ws too small ----------
__global__ void rpi_scatter_kernel(const float* __restrict__ x,
                                   const int* __restrict__ src,
                                   const int* __restrict__ dst,
                                   const float* __restrict__ ew,
                                   int* __restrict__ agg, int E) {
    int tid = blockIdx.x * blockDim.x + threadIdx.x;
    int e = tid >> 4;
    if (e >= E) return;
    int c = (tid & 15) << 2;
    int s = src[e], d = dst[e];
    float w = ew[e] * FP_SCALE;
    float4 v = *reinterpret_cast<const float4*>(&x[(size_t)s * D + c]);
    int* o = &agg[(size_t)d * D + c];
    atomicAdd(o + 0, (int)(w * v.x));
    atomicAdd(o + 1, (int)(w * v.y));
    atomicAdd(o + 2, (int)(w * v.z));
    atomicAdd(o + 3, (int)(w * v.w));
}

__global__ void rpi_linear_relu_kernel(const int* __restrict__ agg,
                                       const float* __restrict__ W,
                                       const float* __restrict__ b,
                                       float* __restrict__ out, int N) {
    __shared__ float Ws[D][D + 1];
    __shared__ float bs[D];
    int t = threadIdx.x;
    for (int i = t; i < D * D; i += 256) Ws[i >> 6][i & 63] = W[i];
    if (t < D) bs[t] = b[t];
    __syncthreads();
    int wave = t >> 6, lane = t & 63;
    int nwaves = gridDim.x * 4;
    for (int n = blockIdx.x * 4 + wave; n < N; n += nwaves) {
        const int* arow = &agg[(size_t)n * D];
        float acc = bs[lane];
        #pragma unroll
        for (int d = 0; d < D; ++d) acc = fmaf((float)arow[d] * FP_INV, Ws[lane][d], acc);
        out[(size_t)n * D + lane] = fmaxf(acc, 0.0f);
    }
}

extern "C" void kernel_launch(void* const* d_in, const int* in_sizes, int n_in,
                              void* d_out, int out_size, void* d_ws, size_t ws_size,
                              hipStream_t stream) {
    const float* x0 = (const float*)d_in[0];   // [N, 64]
    const int*   ei = (const int*)d_in[1];     // [2, E]
    const float* ew = (const float*)d_in[2];   // [E]
    const float* W  = (const float*)d_in[3];   // [64, 64]
    const float* b  = (const float*)d_in[4];   // [64]
    float* out = (float*)d_out;                // [N, 64]

    int N = in_sizes[0] / D;
    int E = in_sizes[2];
    const int* src = ei;
    const int* dst = ei + E;

    int nb   = (N + 255) / 256;
    int nblk = (N + NPC - 1) / NPC;
    size_t xeb = (size_t)N * D * sizeof(unsigned short);   // 12.8 MB
    size_t off = 0;
    size_t o_xb1  = off; off += xeb;
    size_t o_xb2  = off; off += xeb;
    size_t o_p64  = off; off += (size_t)E * sizeof(unsigned long long);
    size_t o_cnt  = off; off += (size_t)N * sizeof(int);
    size_t o_part = off; off += ((size_t)nb + 16) * sizeof(int);
    size_t o_bs   = off; off += ((size_t)nblk + 2) * sizeof(int);
    size_t need = off;

    if (ws_size >= need) {
        unsigned short* xb1 = (unsigned short*)((char*)d_ws + o_xb1);
        unsigned short* xb2 = (unsigned short*)((char*)d_ws + o_xb2);
        unsigned long long* perm64 = (unsigned long long*)((char*)d_ws + o_p64);
        int* cnt_cur    = (int*)((char*)d_ws + o_cnt);   // counts, then cursor
        int* partial    = (int*)((char*)d_ws + o_part);
        int* blockStart = (int*)((char*)d_ws + o_bs);

        int eb = (E + 255) / 256;

        hipMemsetAsync(cnt_cur, 0, (size_t)N * sizeof(int), stream);
        hist_kernel<<<eb, 256, 0, stream>>>(dst, cnt_cur, E);
        part_kernel<<<nb, 256, 0, stream>>>(cnt_cur, partial, N);
        scan_kernel<<<1, 512, 0, stream>>>(partial, nb);
        seg_kernel <<<nb, 256, 0, stream>>>(cnt_cur, partial, cnt_cur, blockStart, N);
        fill_kernel<<<eb, 256, 0, stream>>>(src, dst, ew, cnt_cur, perm64, E);

        // iter 0 reads f32 x0 directly; iters ping-pong bf16
        agg_fused_kernel<true,  true> <<<nblk, 256, 0, stream>>>(x0,  perm64, blockStart, W, b, xb2, N, E);
        agg_fused_kernel<false, true> <<<nblk, 256, 0, stream>>>(xb2, perm64, blockStart, W, b, xb1, N, E);
        agg_fused_kernel<false, false><<<nblk, 256, 0, stream>>>(xb1, perm64, blockStart, W, b, out, N, E);
    } else {
        int* agg = (int*)d_ws;
        const float* xcur = x0;
        int sb = (E * 16 + 255) / 256;
        for (int it = 0; it < 3; ++it) {
            hipMemsetAsync(agg, 0, (size_t)N * D * sizeof(int), stream);
            rpi_scatter_kernel<<<sb, 256, 0, stream>>>(xcur, src, dst, ew, agg, E);
            rpi_linear_relu_kernel<<<2048, 256, 0, stream>>>(agg, W, b, out, N);
            xcur = out;
        }
    }
}